// Round 18
// baseline (74.603 us; speedup 1.0000x reference)
//
#include <hip/hip_runtime.h>
#include <hip/hip_fp16.h>

typedef float v2f __attribute__((ext_vector_type(2)));

constexpr int WIDTH  = 96;
constexpr int HEIGHT = 72;
constexpr int NPTS   = WIDTH * HEIGHT;   // 6912

constexpr int BLOCK  = 128;

// ---- triangle (symmetric) phase: s0 (f1_f1), s1 (f2_f2), s3 (f2_f2_gt) ----
constexpr int TT     = 256;              // square tile edge (2 pts/thread)
constexpr int T      = NPTS / TT;        // 27
constexpr int NPAIR  = T * (T + 1) / 2;  // 378 tile-pairs
constexpr int MCH    = 64;               // m-rows per block
constexpr int NCHT   = TT / MCH;         // 4 chunks per pair
constexpr int NBT    = NPAIR * NCHT;     // 1512 triangle blocks

// ---- full (asymmetric) phase: s2 (f1_f2), s4 (f1_f2_gt) ----
constexpr int NTILE  = 384;              // n-points per block (3/thread)
constexpr int MTILE  = 64;               // m-points per block
constexpr int NTB    = NPTS / NTILE;     // 18
constexpr int MTB    = NPTS / MTILE;     // 108
constexpr int NBF    = NTB * MTB;        // 1944 full blocks

constexpr int NBLK   = NBT + NBF;        // 3456 total

constexpr int ROWT   = 20;               // f32 QT row (A-side reads, 80 B)
constexpr int ROWFN  = 8;                // f32 full n-side row (32 B)
constexpr int R16T   = 32;               // halves per QT16 m-row (64 B, 1 line)
constexpr int R16M   = 16;               // halves per QFm16 m-row (32 B, 1/2 line)

// exp(-0.1*d) = exp2(d * KEXP)
constexpr float KEXP  = -0.14426950408889634f;  // -0.1 * log2(e)
constexpr float M2K   = -2.0f * KEXP;

// QT  (f32): 0..2 xyz1, 3 K|xyz1|^2 | 4..6 xyz2_t, 7 K|..|^2 |
//            8..10 xyz2_gt, 11 K|..|^2 | 12..14 f1, 15..17 f2, 18..19 pad
// QFn (f32): 0..2 M2K*xyz1, 3 K|xyz1|^2, 4..6 f1, 7 pad
// QT16 (f16, m-rows): same 18 values as QT, stride 32 halves (64 B aligned)
// QFm16(f16, m-rows): 0..2 xyz2_t, 3 K|..|^2, 4..6 xyz2_gt, 7 K|..|^2,
//                     8..10 f2, stride 16 halves (32 B)
__global__ __launch_bounds__(256) void precompute_kernel(
    const float* __restrict__ depth1, const float* __restrict__ depth2,
    const float* __restrict__ pose,   const float* __restrict__ img1,
    const float* __restrict__ img2,   const float* __restrict__ poseg,
    float* __restrict__ QT, float* __restrict__ QFn,
    __half* __restrict__ QT16, __half* __restrict__ QFm16)
{
    const int idx = blockIdx.x * 256 + threadIdx.x;

    float R[12], G[12];
#pragma unroll
    for (int i = 0; i < 12; ++i) { R[i] = pose[i]; G[i] = poseg[i]; }

    const int u = idx % WIDTH;
    const int v = idx / WIDTH;
    const float gy = (float)u * (1.0f / 48.0f) - 1.0f;
    const float gz = (float)v * (1.0f / 36.0f) - 1.0f;
    const float d1 = depth1[idx];
    const float d2 = depth2[idx];
    const float x1 = d1, y1 = d1 * gy, z1 = d1 * gz;
    const float x2 = d2, y2 = d2 * gy, z2 = d2 * gz;
    const float xt = R[0] * x2 + R[1] * y2 + R[2]  * z2 + R[3];
    const float yt = R[4] * x2 + R[5] * y2 + R[6]  * z2 + R[7];
    const float zt = R[8] * x2 + R[9] * y2 + R[10] * z2 + R[11];
    const float xg = G[0] * x2 + G[1] * y2 + G[2]  * z2 + G[3];
    const float yg = G[4] * x2 + G[5] * y2 + G[6]  * z2 + G[7];
    const float zg = G[8] * x2 + G[9] * y2 + G[10] * z2 + G[11];

    const float q1 = KEXP * (x1*x1 + y1*y1 + z1*z1);
    const float qt = KEXP * (xt*xt + yt*yt + zt*zt);
    const float qg = KEXP * (xg*xg + yg*yg + zg*zg);
    const float f1a = img1[idx], f1b = img1[NPTS + idx], f1c = img1[2*NPTS + idx];
    const float f2a = img2[idx], f2b = img2[NPTS + idx], f2c = img2[2*NPTS + idx];

    float4* qt_row = (float4*)(QT + (size_t)idx * ROWT);
    qt_row[0] = make_float4(x1, y1, z1, q1);
    qt_row[1] = make_float4(xt, yt, zt, qt);
    qt_row[2] = make_float4(xg, yg, zg, qg);
    qt_row[3] = make_float4(f1a, f1b, f1c, f2a);
    qt_row[4] = make_float4(f2b, f2c, 0.f, 0.f);

    float4* fn_row = (float4*)(QFn + (size_t)idx * ROWFN);
    fn_row[0] = make_float4(M2K * x1, M2K * y1, M2K * z1, q1);
    fn_row[1] = make_float4(f1a, f1b, f1c, 0.f);

    const float ot[18] = {x1, y1, z1, q1, xt, yt, zt, qt, xg, yg, zg, qg,
                          f1a, f1b, f1c, f2a, f2b, f2c};
    __half* t16 = QT16 + (size_t)idx * R16T;
#pragma unroll
    for (int k = 0; k < 18; ++k) t16[k] = __float2half_rn(ot[k]);

    const float om[11] = {xt, yt, zt, qt, xg, yg, zg, qg, f2a, f2b, f2c};
    __half* m16 = QFm16 + (size_t)idx * R16M;
#pragma unroll
    for (int k = 0; k < 11; ++k) m16[k] = __float2half_rn(om[k]);
}

__global__ __launch_bounds__(BLOCK) void pair_kernel(
    const float* __restrict__ QT,  const float* __restrict__ QFn,
    const __half* __restrict__ QT16, const __half* __restrict__ QFm16,
    float* __restrict__ pT, float* __restrict__ pF)
{
    __shared__ float red[2][3];
    const int t = threadIdx.x;

    if (blockIdx.x < NBT) {
        // ------ triangle phase: s0, s1, s3  (2 n-pts/thread, 64 m-rows) ------
        const int pair  = blockIdx.x >> 2;
        const int chunk = blockIdx.x & 3;
        int rem = pair, i = 0;
        while (rem >= T - i) { rem -= T - i; ++i; }   // uniform, <=27 iters
        const int j = i + rem;

        v2f A[18];   // two n-points packed; dot operands pre-scaled by -2K
        {
            const float4* r0 = (const float4*)(QT + (size_t)(i * TT + t) * ROWT);
            const float4* r1 = (const float4*)(QT + (size_t)(i * TT + BLOCK + t) * ROWT);
#pragma unroll
            for (int g = 0; g < 3; ++g) {
                const float4 w0 = r0[g], w1 = r1[g];
                A[4*g+0].x = M2K*w0.x; A[4*g+0].y = M2K*w1.x;
                A[4*g+1].x = M2K*w0.y; A[4*g+1].y = M2K*w1.y;
                A[4*g+2].x = M2K*w0.z; A[4*g+2].y = M2K*w1.z;
                A[4*g+3].x = w0.w;     A[4*g+3].y = w1.w;
            }
            const float4 w30 = r0[3], w31 = r1[3];
            const float4 w40 = r0[4], w41 = r1[4];
            A[12].x=w30.x; A[12].y=w31.x;  A[13].x=w30.y; A[13].y=w31.y;
            A[14].x=w30.z; A[14].y=w31.z;  A[15].x=w30.w; A[15].y=w31.w;
            A[16].x=w40.x; A[16].y=w41.x;  A[17].x=w40.y; A[17].y=w41.y;
        }

        v2f s0 = {0.f, 0.f}, s1 = s0, s3 = s0;
        const __half* __restrict__ q0 =
            QT16 + (size_t)(j * TT + chunk * MCH) * R16T;

#pragma unroll 4
        for (int m = 0; m < MCH; ++m) {
            const __half* __restrict__ bh = q0 + m * R16T;   // wave-uniform, 1 line
            float b[18];
#pragma unroll
            for (int k = 0; k < 18; ++k) b[k] = __half2float(bh[k]);

            v2f t11 = A[3] + b[3];
            t11 = A[0] * b[0] + t11;
            t11 = A[1] * b[1] + t11;
            t11 = A[2] * b[2] + t11;
            v2f t22 = A[7] + b[7];
            t22 = A[4] * b[4] + t22;
            t22 = A[5] * b[5] + t22;
            t22 = A[6] * b[6] + t22;
            v2f tgg = A[11] + b[11];
            tgg = A[8]  * b[8]  + tgg;
            tgg = A[9]  * b[9]  + tgg;
            tgg = A[10] * b[10] + tgg;
            v2f g11 = A[12] * b[12];
            g11 = A[13] * b[13] + g11;
            g11 = A[14] * b[14] + g11;
            v2f g22 = A[15] * b[15];
            g22 = A[16] * b[16] + g22;
            g22 = A[17] * b[17] + g22;
            v2f e11, e22, egg;
            e11.x = __builtin_amdgcn_exp2f(t11.x);
            e11.y = __builtin_amdgcn_exp2f(t11.y);
            e22.x = __builtin_amdgcn_exp2f(t22.x);
            e22.y = __builtin_amdgcn_exp2f(t22.y);
            egg.x = __builtin_amdgcn_exp2f(tgg.x);
            egg.y = __builtin_amdgcn_exp2f(tgg.y);
            s0 = e11 * g11 + s0;
            s1 = e22 * g22 + s1;
            s3 = egg * g22 + s3;
        }
        const float w = (i == j) ? 1.f : 2.f;
        float r0 = w * (s0.x + s0.y);
        float r1 = w * (s1.x + s1.y);
        float r3 = w * (s3.x + s3.y);

#pragma unroll
        for (int off = 32; off > 0; off >>= 1) {
            r0 += __shfl_down(r0, off);
            r1 += __shfl_down(r1, off);
            r3 += __shfl_down(r3, off);
        }
        const int wave = t >> 6, lane = t & 63;
        if (lane == 0) { red[wave][0]=r0; red[wave][1]=r1; red[wave][2]=r3; }
        __syncthreads();
        if (t == 0) {
            pT[0 * NBT + blockIdx.x] = red[0][0] + red[1][0];
            pT[1 * NBT + blockIdx.x] = red[0][1] + red[1][1];
            pT[2 * NBT + blockIdx.x] = red[0][2] + red[1][2];
        }
    } else {
        // ------ full phase: s2, s4  (3 n-pts/thread, 64 m-rows) ------
        const int blk = blockIdx.x - NBT;
        const int bn = blk % NTB;
        const int bm = blk / NTB;

        v2f A2[7];  float A1[7];  // 0..2 M2K*xyz1, 3 K|xyz1|^2, 4..6 f1
        {
            const int n0 = bn * NTILE + t;
            const float4* r0 = (const float4*)(QFn + (size_t)n0 * ROWFN);
            const float4* r1 = (const float4*)(QFn + (size_t)(n0 + BLOCK) * ROWFN);
            const float4* r2 = (const float4*)(QFn + (size_t)(n0 + 2*BLOCK) * ROWFN);
            const float4 a0 = r0[0], a1 = r0[1];
            const float4 c0 = r1[0], c1 = r1[1];
            const float4 d0 = r2[0], d1 = r2[1];
            A2[0].x=a0.x; A2[0].y=c0.x;  A2[1].x=a0.y; A2[1].y=c0.y;
            A2[2].x=a0.z; A2[2].y=c0.z;  A2[3].x=a0.w; A2[3].y=c0.w;
            A2[4].x=a1.x; A2[4].y=c1.x;  A2[5].x=a1.y; A2[5].y=c1.y;
            A2[6].x=a1.z; A2[6].y=c1.z;
            A1[0]=d0.x; A1[1]=d0.y; A1[2]=d0.z; A1[3]=d0.w;
            A1[4]=d1.x; A1[5]=d1.y; A1[6]=d1.z;
        }

        v2f s2v = {0.f, 0.f}, s4v = s2v;
        float s2s = 0.f, s4s = 0.f;
        const __half* __restrict__ q0 = QFm16 + (size_t)(bm * MTILE) * R16M;

#pragma unroll 4
        for (int m = 0; m < MTILE; ++m) {
            const __half* __restrict__ bh = q0 + m * R16M;  // wave-uniform, 1/2 line
            float b[11];
#pragma unroll
            for (int k = 0; k < 11; ++k) b[k] = __half2float(bh[k]);

            v2f t12 = A2[3] + b[3];
            t12 = A2[0] * b[0] + t12;
            t12 = A2[1] * b[1] + t12;
            t12 = A2[2] * b[2] + t12;
            v2f t1g = A2[3] + b[7];
            t1g = A2[0] * b[4] + t1g;
            t1g = A2[1] * b[5] + t1g;
            t1g = A2[2] * b[6] + t1g;
            v2f g12 = A2[4] * b[8];
            g12 = A2[5] * b[9]  + g12;
            g12 = A2[6] * b[10] + g12;
            float u12 = A1[3] + b[3];
            u12 = A1[0] * b[0] + u12;
            u12 = A1[1] * b[1] + u12;
            u12 = A1[2] * b[2] + u12;
            float u1g = A1[3] + b[7];
            u1g = A1[0] * b[4] + u1g;
            u1g = A1[1] * b[5] + u1g;
            u1g = A1[2] * b[6] + u1g;
            float h12 = A1[4] * b[8];
            h12 = A1[5] * b[9]  + h12;
            h12 = A1[6] * b[10] + h12;

            v2f e12, e1g;
            e12.x = __builtin_amdgcn_exp2f(t12.x);
            e12.y = __builtin_amdgcn_exp2f(t12.y);
            e1g.x = __builtin_amdgcn_exp2f(t1g.x);
            e1g.y = __builtin_amdgcn_exp2f(t1g.y);
            const float f12 = __builtin_amdgcn_exp2f(u12);
            const float f1g = __builtin_amdgcn_exp2f(u1g);

            s2v = e12 * g12 + s2v;
            s4v = e1g * g12 + s4v;
            s2s = f12 * h12 + s2s;
            s4s = f1g * h12 + s4s;
        }

        float r2 = s2v.x + s2v.y + s2s;
        float r4 = s4v.x + s4v.y + s4s;
#pragma unroll
        for (int off = 32; off > 0; off >>= 1) {
            r2 += __shfl_down(r2, off);
            r4 += __shfl_down(r4, off);
        }
        const int wave = t >> 6, lane = t & 63;
        if (lane == 0) { red[wave][0] = r2; red[wave][1] = r4; }
        __syncthreads();
        if (t == 0) {
            pF[0 * NBF + blk] = red[0][0] + red[1][0];
            pF[1 * NBF + blk] = red[0][1] + red[1][1];
        }
    }
}

__global__ __launch_bounds__(256) void finalize_kernel(
    const float* __restrict__ pT, const float* __restrict__ pF,
    float* __restrict__ out)
{
    __shared__ double red[4][5];
    double l0 = 0, l1 = 0, l2 = 0, l3 = 0, l4 = 0;
    for (int b = threadIdx.x; b < NBT; b += 256) {
        l0 += pT[0 * NBT + b];
        l1 += pT[1 * NBT + b];
        l3 += pT[2 * NBT + b];
    }
    for (int b = threadIdx.x; b < NBF; b += 256) {
        l2 += pF[0 * NBF + b];
        l4 += pF[1 * NBF + b];
    }
#pragma unroll
    for (int off = 32; off > 0; off >>= 1) {
        l0 += __shfl_down(l0, off);
        l1 += __shfl_down(l1, off);
        l2 += __shfl_down(l2, off);
        l3 += __shfl_down(l3, off);
        l4 += __shfl_down(l4, off);
    }
    const int wave = threadIdx.x >> 6, lane = threadIdx.x & 63;
    if (lane == 0) {
        red[wave][0] = l0; red[wave][1] = l1; red[wave][2] = l2;
        red[wave][3] = l3; red[wave][4] = l4;
    }
    __syncthreads();
    if (threadIdx.x == 0) {
        const double a0 = red[0][0] + red[1][0] + red[2][0] + red[3][0];
        const double a1 = red[0][1] + red[1][1] + red[2][1] + red[3][1];
        const double a2 = red[0][2] + red[1][2] + red[2][2] + red[3][2];
        const double a3 = red[0][3] + red[1][3] + red[2][3] + red[3][3];
        const double a4 = red[0][4] + red[1][4] + red[2][4] + red[3][4];
        const double num = a0 + a1 - 2.0 * a2;
        const double den = a0 + a3 - 2.0 * a4;
        out[0] = (float)(num / den);
    }
}

extern "C" void kernel_launch(void* const* d_in, const int* in_sizes, int n_in,
                              void* d_out, int out_size, void* d_ws, size_t ws_size,
                              hipStream_t stream)
{
    const float* depth1 = (const float*)d_in[0];
    const float* depth2 = (const float*)d_in[1];
    const float* pose   = (const float*)d_in[2];
    const float* img1   = (const float*)d_in[3];
    const float* img2   = (const float*)d_in[4];
    const float* poseg  = (const float*)d_in[5];

    float*  QT    = (float*)d_ws;                       // 6912*20 f = 553 KB
    float*  QFn   = QT + (size_t)NPTS * ROWT;           // 6912* 8 f = 221 KB
    __half* QT16  = (__half*)(QFn + (size_t)NPTS * ROWFN);   // 6912*32 h = 442 KB
    __half* QFm16 = QT16 + (size_t)NPTS * R16T;              // 6912*16 h = 221 KB
    float*  pT    = (float*)(QFm16 + (size_t)NPTS * R16M);   // 3*1512 f
    float*  pF    = pT + 3 * NBT;                            // 2*1944 f

    precompute_kernel<<<NPTS / 256, 256, 0, stream>>>(depth1, depth2, pose,
                                                      img1, img2, poseg,
                                                      QT, QFn, QT16, QFm16);
    pair_kernel<<<NBLK, BLOCK, 0, stream>>>(QT, QFn, QT16, QFm16, pT, pF);
    finalize_kernel<<<1, 256, 0, stream>>>(pT, pF, (float*)d_out);
}

// Round 19
// 61.249 us; speedup vs baseline: 1.2180x; 1.2180x over previous
//
#include <hip/hip_runtime.h>
#include <hip/hip_fp16.h>

typedef float v2f __attribute__((ext_vector_type(2)));

constexpr int WIDTH  = 96;
constexpr int HEIGHT = 72;
constexpr int NPTS   = WIDTH * HEIGHT;   // 6912

constexpr int BLOCK  = 128;

// ---- triangle (symmetric) phase: s0 (f1_f1), s1 (f2_f2), s3 (f2_f2_gt) ----
constexpr int TT     = 256;              // square tile edge (2 pts/thread)
constexpr int T      = NPTS / TT;        // 27
constexpr int NPAIR  = T * (T + 1) / 2;  // 378 tile-pairs
constexpr int MCH    = 64;               // m-rows per block
constexpr int NCHT   = TT / MCH;         // 4 chunks per pair
constexpr int NBT    = NPAIR * NCHT;     // 1512 triangle blocks

// ---- full (asymmetric) phase: s2 (f1_f2), s4 (f1_f2_gt) ----
constexpr int NTILE  = 384;              // n-points per block (3/thread)
constexpr int MTILE  = 64;               // m-points per block
constexpr int NTB    = NPTS / NTILE;     // 18
constexpr int MTB    = NPTS / MTILE;     // 108
constexpr int NBF    = NTB * MTB;        // 1944 full blocks

constexpr int NBLK   = NBT + NBF;        // 3456 total

constexpr int ROWT   = 20;               // f32 QT row (A-side reads, 80 B)
constexpr int ROWFN  = 8;                // f32 full n-side row (32 B)
constexpr int RPT    = 12;               // dwords per packed triangle m-row (48 B)
constexpr int RPM    = 8;                // dwords per packed full m-row (32 B)

// exp(-0.1*d) = exp2(d * KEXP)
constexpr float KEXP  = -0.14426950408889634f;  // -0.1 * log2(e)
constexpr float M2K   = -2.0f * KEXP;

__device__ __forceinline__ unsigned int pack2(float a, float b) {
    const unsigned short lo = __half_as_ushort(__float2half_rn(a));
    const unsigned short hi = __half_as_ushort(__float2half_rn(b));
    return (unsigned int)lo | ((unsigned int)hi << 16);
}
__device__ __forceinline__ float unlo(unsigned int d) {
    return __half2float(__ushort_as_half((unsigned short)(d & 0xffffu)));
}
__device__ __forceinline__ float unhi(unsigned int d) {
    return __half2float(__ushort_as_half((unsigned short)(d >> 16)));
}

// QT  (f32): 0..2 xyz1, 3 K|xyz1|^2 | 4..6 xyz2_t, 7 K|..|^2 |
//            8..10 xyz2_gt, 11 K|..|^2 | 12..14 f1, 15..17 f2, 18..19 pad
// QFn (f32): 0..2 M2K*xyz1, 3 K|xyz1|^2, 4..6 f1, 7 pad
// QTp (packed f16 pairs in uint): 9 data dwords (18 values), stride 12 dwords
// QFmp(packed): 6 data dwords (11 values + pad), stride 8 dwords
__global__ __launch_bounds__(256) void precompute_kernel(
    const float* __restrict__ depth1, const float* __restrict__ depth2,
    const float* __restrict__ pose,   const float* __restrict__ img1,
    const float* __restrict__ img2,   const float* __restrict__ poseg,
    float* __restrict__ QT, float* __restrict__ QFn,
    unsigned int* __restrict__ QTp, unsigned int* __restrict__ QFmp)
{
    const int idx = blockIdx.x * 256 + threadIdx.x;

    float R[12], G[12];
#pragma unroll
    for (int i = 0; i < 12; ++i) { R[i] = pose[i]; G[i] = poseg[i]; }

    const int u = idx % WIDTH;
    const int v = idx / WIDTH;
    const float gy = (float)u * (1.0f / 48.0f) - 1.0f;
    const float gz = (float)v * (1.0f / 36.0f) - 1.0f;
    const float d1 = depth1[idx];
    const float d2 = depth2[idx];
    const float x1 = d1, y1 = d1 * gy, z1 = d1 * gz;
    const float x2 = d2, y2 = d2 * gy, z2 = d2 * gz;
    const float xt = R[0] * x2 + R[1] * y2 + R[2]  * z2 + R[3];
    const float yt = R[4] * x2 + R[5] * y2 + R[6]  * z2 + R[7];
    const float zt = R[8] * x2 + R[9] * y2 + R[10] * z2 + R[11];
    const float xg = G[0] * x2 + G[1] * y2 + G[2]  * z2 + G[3];
    const float yg = G[4] * x2 + G[5] * y2 + G[6]  * z2 + G[7];
    const float zg = G[8] * x2 + G[9] * y2 + G[10] * z2 + G[11];

    const float q1 = KEXP * (x1*x1 + y1*y1 + z1*z1);
    const float qt = KEXP * (xt*xt + yt*yt + zt*zt);
    const float qg = KEXP * (xg*xg + yg*yg + zg*zg);
    const float f1a = img1[idx], f1b = img1[NPTS + idx], f1c = img1[2*NPTS + idx];
    const float f2a = img2[idx], f2b = img2[NPTS + idx], f2c = img2[2*NPTS + idx];

    float4* qt_row = (float4*)(QT + (size_t)idx * ROWT);
    qt_row[0] = make_float4(x1, y1, z1, q1);
    qt_row[1] = make_float4(xt, yt, zt, qt);
    qt_row[2] = make_float4(xg, yg, zg, qg);
    qt_row[3] = make_float4(f1a, f1b, f1c, f2a);
    qt_row[4] = make_float4(f2b, f2c, 0.f, 0.f);

    float4* fn_row = (float4*)(QFn + (size_t)idx * ROWFN);
    fn_row[0] = make_float4(M2K * x1, M2K * y1, M2K * z1, q1);
    fn_row[1] = make_float4(f1a, f1b, f1c, 0.f);

    const float ot[18] = {x1, y1, z1, q1, xt, yt, zt, qt, xg, yg, zg, qg,
                          f1a, f1b, f1c, f2a, f2b, f2c};
    unsigned int* tp = QTp + (size_t)idx * RPT;
#pragma unroll
    for (int k = 0; k < 9; ++k) tp[k] = pack2(ot[2*k], ot[2*k+1]);

    const float om[12] = {xt, yt, zt, qt, xg, yg, zg, qg, f2a, f2b, f2c, 0.f};
    unsigned int* mp = QFmp + (size_t)idx * RPM;
#pragma unroll
    for (int k = 0; k < 6; ++k) mp[k] = pack2(om[2*k], om[2*k+1]);
}

__global__ __launch_bounds__(BLOCK) void pair_kernel(
    const float* __restrict__ QT,  const float* __restrict__ QFn,
    const unsigned int* __restrict__ QTp, const unsigned int* __restrict__ QFmp,
    float* __restrict__ pT, float* __restrict__ pF)
{
    __shared__ float red[2][3];
    const int t = threadIdx.x;

    if (blockIdx.x < NBT) {
        // ------ triangle phase: s0, s1, s3  (2 n-pts/thread, 64 m-rows) ------
        const int pair  = blockIdx.x >> 2;
        const int chunk = blockIdx.x & 3;
        int rem = pair, i = 0;
        while (rem >= T - i) { rem -= T - i; ++i; }   // uniform, <=27 iters
        const int j = i + rem;

        v2f A[18];   // two n-points packed; dot operands pre-scaled by -2K
        {
            const float4* r0 = (const float4*)(QT + (size_t)(i * TT + t) * ROWT);
            const float4* r1 = (const float4*)(QT + (size_t)(i * TT + BLOCK + t) * ROWT);
#pragma unroll
            for (int g = 0; g < 3; ++g) {
                const float4 w0 = r0[g], w1 = r1[g];
                A[4*g+0].x = M2K*w0.x; A[4*g+0].y = M2K*w1.x;
                A[4*g+1].x = M2K*w0.y; A[4*g+1].y = M2K*w1.y;
                A[4*g+2].x = M2K*w0.z; A[4*g+2].y = M2K*w1.z;
                A[4*g+3].x = w0.w;     A[4*g+3].y = w1.w;
            }
            const float4 w30 = r0[3], w31 = r1[3];
            const float4 w40 = r0[4], w41 = r1[4];
            A[12].x=w30.x; A[12].y=w31.x;  A[13].x=w30.y; A[13].y=w31.y;
            A[14].x=w30.z; A[14].y=w31.z;  A[15].x=w30.w; A[15].y=w31.w;
            A[16].x=w40.x; A[16].y=w41.x;  A[17].x=w40.y; A[17].y=w41.y;
        }

        v2f s0 = {0.f, 0.f}, s1 = s0, s3 = s0;
        const unsigned int* __restrict__ q0 =
            QTp + (size_t)(j * TT + chunk * MCH) * RPT;

        // unroll 8: 8 rows x 9 dwords = 72 SGPRs of packed b-data per drain
#pragma unroll 8
        for (int m = 0; m < MCH; ++m) {
            const unsigned int* __restrict__ bp = q0 + m * RPT;  // wave-uniform
            unsigned int dw[9];
#pragma unroll
            for (int k = 0; k < 9; ++k) dw[k] = bp[k];
            float b[18];
#pragma unroll
            for (int k = 0; k < 9; ++k) { b[2*k] = unlo(dw[k]); b[2*k+1] = unhi(dw[k]); }

            v2f t11 = A[3] + b[3];
            t11 = A[0] * b[0] + t11;
            t11 = A[1] * b[1] + t11;
            t11 = A[2] * b[2] + t11;
            v2f t22 = A[7] + b[7];
            t22 = A[4] * b[4] + t22;
            t22 = A[5] * b[5] + t22;
            t22 = A[6] * b[6] + t22;
            v2f tgg = A[11] + b[11];
            tgg = A[8]  * b[8]  + tgg;
            tgg = A[9]  * b[9]  + tgg;
            tgg = A[10] * b[10] + tgg;
            v2f g11 = A[12] * b[12];
            g11 = A[13] * b[13] + g11;
            g11 = A[14] * b[14] + g11;
            v2f g22 = A[15] * b[15];
            g22 = A[16] * b[16] + g22;
            g22 = A[17] * b[17] + g22;
            v2f e11, e22, egg;
            e11.x = __builtin_amdgcn_exp2f(t11.x);
            e11.y = __builtin_amdgcn_exp2f(t11.y);
            e22.x = __builtin_amdgcn_exp2f(t22.x);
            e22.y = __builtin_amdgcn_exp2f(t22.y);
            egg.x = __builtin_amdgcn_exp2f(tgg.x);
            egg.y = __builtin_amdgcn_exp2f(tgg.y);
            s0 = e11 * g11 + s0;
            s1 = e22 * g22 + s1;
            s3 = egg * g22 + s3;
        }
        const float w = (i == j) ? 1.f : 2.f;
        float r0 = w * (s0.x + s0.y);
        float r1 = w * (s1.x + s1.y);
        float r3 = w * (s3.x + s3.y);

#pragma unroll
        for (int off = 32; off > 0; off >>= 1) {
            r0 += __shfl_down(r0, off);
            r1 += __shfl_down(r1, off);
            r3 += __shfl_down(r3, off);
        }
        const int wave = t >> 6, lane = t & 63;
        if (lane == 0) { red[wave][0]=r0; red[wave][1]=r1; red[wave][2]=r3; }
        __syncthreads();
        if (t == 0) {
            pT[0 * NBT + blockIdx.x] = red[0][0] + red[1][0];
            pT[1 * NBT + blockIdx.x] = red[0][1] + red[1][1];
            pT[2 * NBT + blockIdx.x] = red[0][2] + red[1][2];
        }
    } else {
        // ------ full phase: s2, s4  (3 n-pts/thread, 64 m-rows) ------
        const int blk = blockIdx.x - NBT;
        const int bn = blk % NTB;
        const int bm = blk / NTB;

        v2f A2[7];  float A1[7];  // 0..2 M2K*xyz1, 3 K|xyz1|^2, 4..6 f1
        {
            const int n0 = bn * NTILE + t;
            const float4* r0 = (const float4*)(QFn + (size_t)n0 * ROWFN);
            const float4* r1 = (const float4*)(QFn + (size_t)(n0 + BLOCK) * ROWFN);
            const float4* r2 = (const float4*)(QFn + (size_t)(n0 + 2*BLOCK) * ROWFN);
            const float4 a0 = r0[0], a1 = r0[1];
            const float4 c0 = r1[0], c1 = r1[1];
            const float4 d0 = r2[0], d1 = r2[1];
            A2[0].x=a0.x; A2[0].y=c0.x;  A2[1].x=a0.y; A2[1].y=c0.y;
            A2[2].x=a0.z; A2[2].y=c0.z;  A2[3].x=a0.w; A2[3].y=c0.w;
            A2[4].x=a1.x; A2[4].y=c1.x;  A2[5].x=a1.y; A2[5].y=c1.y;
            A2[6].x=a1.z; A2[6].y=c1.z;
            A1[0]=d0.x; A1[1]=d0.y; A1[2]=d0.z; A1[3]=d0.w;
            A1[4]=d1.x; A1[5]=d1.y; A1[6]=d1.z;
        }

        v2f s2v = {0.f, 0.f}, s4v = s2v;
        float s2s = 0.f, s4s = 0.f;
        const unsigned int* __restrict__ q0 = QFmp + (size_t)(bm * MTILE) * RPM;

        // unroll 8: 8 rows x 6 dwords = 48 SGPRs of packed b-data per drain
#pragma unroll 8
        for (int m = 0; m < MTILE; ++m) {
            const unsigned int* __restrict__ bp = q0 + m * RPM;  // wave-uniform
            unsigned int dw[6];
#pragma unroll
            for (int k = 0; k < 6; ++k) dw[k] = bp[k];
            float b[11];
#pragma unroll
            for (int k = 0; k < 5; ++k) { b[2*k] = unlo(dw[k]); b[2*k+1] = unhi(dw[k]); }
            b[10] = unlo(dw[5]);

            v2f t12 = A2[3] + b[3];
            t12 = A2[0] * b[0] + t12;
            t12 = A2[1] * b[1] + t12;
            t12 = A2[2] * b[2] + t12;
            v2f t1g = A2[3] + b[7];
            t1g = A2[0] * b[4] + t1g;
            t1g = A2[1] * b[5] + t1g;
            t1g = A2[2] * b[6] + t1g;
            v2f g12 = A2[4] * b[8];
            g12 = A2[5] * b[9]  + g12;
            g12 = A2[6] * b[10] + g12;
            float u12 = A1[3] + b[3];
            u12 = A1[0] * b[0] + u12;
            u12 = A1[1] * b[1] + u12;
            u12 = A1[2] * b[2] + u12;
            float u1g = A1[3] + b[7];
            u1g = A1[0] * b[4] + u1g;
            u1g = A1[1] * b[5] + u1g;
            u1g = A1[2] * b[6] + u1g;
            float h12 = A1[4] * b[8];
            h12 = A1[5] * b[9]  + h12;
            h12 = A1[6] * b[10] + h12;

            v2f e12, e1g;
            e12.x = __builtin_amdgcn_exp2f(t12.x);
            e12.y = __builtin_amdgcn_exp2f(t12.y);
            e1g.x = __builtin_amdgcn_exp2f(t1g.x);
            e1g.y = __builtin_amdgcn_exp2f(t1g.y);
            const float f12 = __builtin_amdgcn_exp2f(u12);
            const float f1g = __builtin_amdgcn_exp2f(u1g);

            s2v = e12 * g12 + s2v;
            s4v = e1g * g12 + s4v;
            s2s = f12 * h12 + s2s;
            s4s = f1g * h12 + s4s;
        }

        float r2 = s2v.x + s2v.y + s2s;
        float r4 = s4v.x + s4v.y + s4s;
#pragma unroll
        for (int off = 32; off > 0; off >>= 1) {
            r2 += __shfl_down(r2, off);
            r4 += __shfl_down(r4, off);
        }
        const int wave = t >> 6, lane = t & 63;
        if (lane == 0) { red[wave][0] = r2; red[wave][1] = r4; }
        __syncthreads();
        if (t == 0) {
            pF[0 * NBF + blk] = red[0][0] + red[1][0];
            pF[1 * NBF + blk] = red[0][1] + red[1][1];
        }
    }
}

__global__ __launch_bounds__(256) void finalize_kernel(
    const float* __restrict__ pT, const float* __restrict__ pF,
    float* __restrict__ out)
{
    __shared__ double red[4][5];
    double l0 = 0, l1 = 0, l2 = 0, l3 = 0, l4 = 0;
    for (int b = threadIdx.x; b < NBT; b += 256) {
        l0 += pT[0 * NBT + b];
        l1 += pT[1 * NBT + b];
        l3 += pT[2 * NBT + b];
    }
    for (int b = threadIdx.x; b < NBF; b += 256) {
        l2 += pF[0 * NBF + b];
        l4 += pF[1 * NBF + b];
    }
#pragma unroll
    for (int off = 32; off > 0; off >>= 1) {
        l0 += __shfl_down(l0, off);
        l1 += __shfl_down(l1, off);
        l2 += __shfl_down(l2, off);
        l3 += __shfl_down(l3, off);
        l4 += __shfl_down(l4, off);
    }
    const int wave = threadIdx.x >> 6, lane = threadIdx.x & 63;
    if (lane == 0) {
        red[wave][0] = l0; red[wave][1] = l1; red[wave][2] = l2;
        red[wave][3] = l3; red[wave][4] = l4;
    }
    __syncthreads();
    if (threadIdx.x == 0) {
        const double a0 = red[0][0] + red[1][0] + red[2][0] + red[3][0];
        const double a1 = red[0][1] + red[1][1] + red[2][1] + red[3][1];
        const double a2 = red[0][2] + red[1][2] + red[2][2] + red[3][2];
        const double a3 = red[0][3] + red[1][3] + red[2][3] + red[3][3];
        const double a4 = red[0][4] + red[1][4] + red[2][4] + red[3][4];
        const double num = a0 + a1 - 2.0 * a2;
        const double den = a0 + a3 - 2.0 * a4;
        out[0] = (float)(num / den);
    }
}

extern "C" void kernel_launch(void* const* d_in, const int* in_sizes, int n_in,
                              void* d_out, int out_size, void* d_ws, size_t ws_size,
                              hipStream_t stream)
{
    const float* depth1 = (const float*)d_in[0];
    const float* depth2 = (const float*)d_in[1];
    const float* pose   = (const float*)d_in[2];
    const float* img1   = (const float*)d_in[3];
    const float* img2   = (const float*)d_in[4];
    const float* poseg  = (const float*)d_in[5];

    float* QT  = (float*)d_ws;                          // 6912*20 f = 553 KB
    float* QFn = QT + (size_t)NPTS * ROWT;              // 6912* 8 f = 221 KB
    unsigned int* QTp  = (unsigned int*)(QFn + (size_t)NPTS * ROWFN); // 332 KB
    unsigned int* QFmp = QTp + (size_t)NPTS * RPT;      // 6912*8 u = 221 KB
    float* pT  = (float*)(QFmp + (size_t)NPTS * RPM);   // 3*1512 f
    float* pF  = pT + 3 * NBT;                          // 2*1944 f

    precompute_kernel<<<NPTS / 256, 256, 0, stream>>>(depth1, depth2, pose,
                                                      img1, img2, poseg,
                                                      QT, QFn, QTp, QFmp);
    pair_kernel<<<NBLK, BLOCK, 0, stream>>>(QT, QFn, QTp, QFmp, pT, pF);
    finalize_kernel<<<1, 256, 0, stream>>>(pT, pF, (float*)d_out);
}

// Round 20
// 51.703 us; speedup vs baseline: 1.4429x; 1.1846x over previous
//
#include <hip/hip_runtime.h>

typedef float v2f __attribute__((ext_vector_type(2)));

constexpr int WIDTH  = 96;
constexpr int HEIGHT = 72;
constexpr int NPTS   = WIDTH * HEIGHT;   // 6912

constexpr int BLOCK  = 128;

// ---- triangle (symmetric) phase: s0 (f1_f1), s1 (f2_f2), s3 (f2_f2_gt) ----
constexpr int TT     = 256;              // square tile edge (2 pts/thread)
constexpr int T      = NPTS / TT;        // 27
constexpr int NPAIR  = T * (T + 1) / 2;  // 378 tile-pairs
constexpr int MCH    = 64;               // m-rows per block
constexpr int NCHT   = TT / MCH;         // 4 chunks per pair
constexpr int NBT    = NPAIR * NCHT;     // 1512 triangle blocks

// ---- full (asymmetric) phase: s2 (f1_f2), s4 (f1_f2_gt) ----
constexpr int NTILE  = 384;              // n-points per block (3/thread)
constexpr int MTILE  = 64;               // m-points per block
constexpr int NTB    = NPTS / NTILE;     // 18
constexpr int MTB    = NPTS / MTILE;     // 108
constexpr int NBF    = NTB * MTB;        // 1944 full blocks

constexpr int NBLK   = NBT + NBF;        // 3456 total

constexpr int ROWT   = 20;               // triangle table row (80 B)
constexpr int ROWFN  = 8;                // full n-side row (32 B)
constexpr int ROWFM  = 12;               // full m-side row (48 B)

// exp(-0.1*d) = exp2(d * KEXP)
constexpr float KEXP  = -0.14426950408889634f;  // -0.1 * log2(e)
constexpr float M2K   = -2.0f * KEXP;

// QT row: 0..2 xyz1, 3 K|xyz1|^2 | 4..6 xyz2_t, 7 K|..|^2 |
//         8..10 xyz2_gt, 11 K|..|^2 | 12..14 f1, 15..17 f2, 18..19 pad
// QFn row: 0..2 M2K*xyz1, 3 K|xyz1|^2, 4..6 f1, 7 pad
// QFm row: 0..2 xyz2_t, 3 K|..|^2, 4..6 xyz2_gt, 7 K|..|^2, 8..10 f2, 11 pad
__global__ __launch_bounds__(256) void precompute_kernel(
    const float* __restrict__ depth1, const float* __restrict__ depth2,
    const float* __restrict__ pose,   const float* __restrict__ img1,
    const float* __restrict__ img2,   const float* __restrict__ poseg,
    float* __restrict__ QT, float* __restrict__ QFn, float* __restrict__ QFm)
{
    const int idx = blockIdx.x * 256 + threadIdx.x;

    float R[12], G[12];
#pragma unroll
    for (int i = 0; i < 12; ++i) { R[i] = pose[i]; G[i] = poseg[i]; }

    const int u = idx % WIDTH;
    const int v = idx / WIDTH;
    const float gy = (float)u * (1.0f / 48.0f) - 1.0f;
    const float gz = (float)v * (1.0f / 36.0f) - 1.0f;
    const float d1 = depth1[idx];
    const float d2 = depth2[idx];
    const float x1 = d1, y1 = d1 * gy, z1 = d1 * gz;
    const float x2 = d2, y2 = d2 * gy, z2 = d2 * gz;
    const float xt = R[0] * x2 + R[1] * y2 + R[2]  * z2 + R[3];
    const float yt = R[4] * x2 + R[5] * y2 + R[6]  * z2 + R[7];
    const float zt = R[8] * x2 + R[9] * y2 + R[10] * z2 + R[11];
    const float xg = G[0] * x2 + G[1] * y2 + G[2]  * z2 + G[3];
    const float yg = G[4] * x2 + G[5] * y2 + G[6]  * z2 + G[7];
    const float zg = G[8] * x2 + G[9] * y2 + G[10] * z2 + G[11];

    const float q1 = KEXP * (x1*x1 + y1*y1 + z1*z1);
    const float qt = KEXP * (xt*xt + yt*yt + zt*zt);
    const float qg = KEXP * (xg*xg + yg*yg + zg*zg);
    const float f1a = img1[idx], f1b = img1[NPTS + idx], f1c = img1[2*NPTS + idx];
    const float f2a = img2[idx], f2b = img2[NPTS + idx], f2c = img2[2*NPTS + idx];

    float4* qt_row = (float4*)(QT + (size_t)idx * ROWT);
    qt_row[0] = make_float4(x1, y1, z1, q1);
    qt_row[1] = make_float4(xt, yt, zt, qt);
    qt_row[2] = make_float4(xg, yg, zg, qg);
    qt_row[3] = make_float4(f1a, f1b, f1c, f2a);
    qt_row[4] = make_float4(f2b, f2c, 0.f, 0.f);

    float4* fn_row = (float4*)(QFn + (size_t)idx * ROWFN);
    fn_row[0] = make_float4(M2K * x1, M2K * y1, M2K * z1, q1);
    fn_row[1] = make_float4(f1a, f1b, f1c, 0.f);

    float4* fm_row = (float4*)(QFm + (size_t)idx * ROWFM);
    fm_row[0] = make_float4(xt, yt, zt, qt);
    fm_row[1] = make_float4(xg, yg, zg, qg);
    fm_row[2] = make_float4(f2a, f2b, f2c, 0.f);
}

__global__ __launch_bounds__(BLOCK) void pair_kernel(
    const float* __restrict__ QT,  const float* __restrict__ QFn,
    const float* __restrict__ QFm,
    float* __restrict__ pT, float* __restrict__ pF)
{
    __shared__ float red[2][3];
    const int t = threadIdx.x;

    if (blockIdx.x < NBT) {
        // ------ triangle phase: s0, s1, s3  (2 n-pts/thread, 64 m-rows) ------
        const int pair  = blockIdx.x >> 2;
        const int chunk = blockIdx.x & 3;
        int rem = pair, i = 0;
        while (rem >= T - i) { rem -= T - i; ++i; }   // uniform, <=27 iters
        const int j = i + rem;

        v2f A[18];   // two n-points packed; dot operands pre-scaled by -2K
        {
            const float4* r0 = (const float4*)(QT + (size_t)(i * TT + t) * ROWT);
            const float4* r1 = (const float4*)(QT + (size_t)(i * TT + BLOCK + t) * ROWT);
#pragma unroll
            for (int g = 0; g < 3; ++g) {
                const float4 w0 = r0[g], w1 = r1[g];
                A[4*g+0].x = M2K*w0.x; A[4*g+0].y = M2K*w1.x;
                A[4*g+1].x = M2K*w0.y; A[4*g+1].y = M2K*w1.y;
                A[4*g+2].x = M2K*w0.z; A[4*g+2].y = M2K*w1.z;
                A[4*g+3].x = w0.w;     A[4*g+3].y = w1.w;
            }
            const float4 w30 = r0[3], w31 = r1[3];
            const float4 w40 = r0[4], w41 = r1[4];
            A[12].x=w30.x; A[12].y=w31.x;  A[13].x=w30.y; A[13].y=w31.y;
            A[14].x=w30.z; A[14].y=w31.z;  A[15].x=w30.w; A[15].y=w31.w;
            A[16].x=w40.x; A[16].y=w41.x;  A[17].x=w40.y; A[17].y=w41.y;
        }

        v2f s0 = {0.f, 0.f}, s1 = s0, s3 = s0;
        const float* __restrict__ q0 =
            QT + (size_t)(j * TT + chunk * MCH) * ROWT;

        // unroll 4: batch 4 rows of uniform s_loads per lgkmcnt drain
#pragma unroll 4
        for (int m = 0; m < MCH; ++m) {
            const float* __restrict__ b = q0 + m * ROWT;   // wave-uniform
            v2f t11 = A[3] + b[3];
            t11 = A[0] * b[0] + t11;
            t11 = A[1] * b[1] + t11;
            t11 = A[2] * b[2] + t11;
            v2f t22 = A[7] + b[7];
            t22 = A[4] * b[4] + t22;
            t22 = A[5] * b[5] + t22;
            t22 = A[6] * b[6] + t22;
            v2f tgg = A[11] + b[11];
            tgg = A[8]  * b[8]  + tgg;
            tgg = A[9]  * b[9]  + tgg;
            tgg = A[10] * b[10] + tgg;
            v2f g11 = A[12] * b[12];
            g11 = A[13] * b[13] + g11;
            g11 = A[14] * b[14] + g11;
            v2f g22 = A[15] * b[15];
            g22 = A[16] * b[16] + g22;
            g22 = A[17] * b[17] + g22;
            v2f e11, e22, egg;
            e11.x = __builtin_amdgcn_exp2f(t11.x);
            e11.y = __builtin_amdgcn_exp2f(t11.y);
            e22.x = __builtin_amdgcn_exp2f(t22.x);
            e22.y = __builtin_amdgcn_exp2f(t22.y);
            egg.x = __builtin_amdgcn_exp2f(tgg.x);
            egg.y = __builtin_amdgcn_exp2f(tgg.y);
            s0 = e11 * g11 + s0;
            s1 = e22 * g22 + s1;
            s3 = egg * g22 + s3;
        }
        const float w = (i == j) ? 1.f : 2.f;
        float r0 = w * (s0.x + s0.y);
        float r1 = w * (s1.x + s1.y);
        float r3 = w * (s3.x + s3.y);

#pragma unroll
        for (int off = 32; off > 0; off >>= 1) {
            r0 += __shfl_down(r0, off);
            r1 += __shfl_down(r1, off);
            r3 += __shfl_down(r3, off);
        }
        const int wave = t >> 6, lane = t & 63;
        if (lane == 0) { red[wave][0]=r0; red[wave][1]=r1; red[wave][2]=r3; }
        __syncthreads();
        if (t == 0) {
            pT[0 * NBT + blockIdx.x] = red[0][0] + red[1][0];
            pT[1 * NBT + blockIdx.x] = red[0][1] + red[1][1];
            pT[2 * NBT + blockIdx.x] = red[0][2] + red[1][2];
        }
    } else {
        // ------ full phase: s2, s4  (3 n-pts/thread, 64 m-rows) ------
        const int blk = blockIdx.x - NBT;
        const int bn = blk % NTB;
        const int bm = blk / NTB;

        v2f A2[7];  float A1[7];  // 0..2 M2K*xyz1, 3 K|xyz1|^2, 4..6 f1
        {
            const int n0 = bn * NTILE + t;
            const float4* r0 = (const float4*)(QFn + (size_t)n0 * ROWFN);
            const float4* r1 = (const float4*)(QFn + (size_t)(n0 + BLOCK) * ROWFN);
            const float4* r2 = (const float4*)(QFn + (size_t)(n0 + 2*BLOCK) * ROWFN);
            const float4 a0 = r0[0], a1 = r0[1];
            const float4 c0 = r1[0], c1 = r1[1];
            const float4 d0 = r2[0], d1 = r2[1];
            A2[0].x=a0.x; A2[0].y=c0.x;  A2[1].x=a0.y; A2[1].y=c0.y;
            A2[2].x=a0.z; A2[2].y=c0.z;  A2[3].x=a0.w; A2[3].y=c0.w;
            A2[4].x=a1.x; A2[4].y=c1.x;  A2[5].x=a1.y; A2[5].y=c1.y;
            A2[6].x=a1.z; A2[6].y=c1.z;
            A1[0]=d0.x; A1[1]=d0.y; A1[2]=d0.z; A1[3]=d0.w;
            A1[4]=d1.x; A1[5]=d1.y; A1[6]=d1.z;
        }

        v2f s2v = {0.f, 0.f}, s4v = s2v;
        float s2s = 0.f, s4s = 0.f;
        const float* __restrict__ q0 = QFm + (size_t)(bm * MTILE) * ROWFM;

#pragma unroll 4
        for (int m = 0; m < MTILE; ++m) {
            const float* __restrict__ b = q0 + m * ROWFM;  // wave-uniform
            v2f t12 = A2[3] + b[3];
            t12 = A2[0] * b[0] + t12;
            t12 = A2[1] * b[1] + t12;
            t12 = A2[2] * b[2] + t12;
            v2f t1g = A2[3] + b[7];
            t1g = A2[0] * b[4] + t1g;
            t1g = A2[1] * b[5] + t1g;
            t1g = A2[2] * b[6] + t1g;
            v2f g12 = A2[4] * b[8];
            g12 = A2[5] * b[9]  + g12;
            g12 = A2[6] * b[10] + g12;
            float u12 = A1[3] + b[3];
            u12 = A1[0] * b[0] + u12;
            u12 = A1[1] * b[1] + u12;
            u12 = A1[2] * b[2] + u12;
            float u1g = A1[3] + b[7];
            u1g = A1[0] * b[4] + u1g;
            u1g = A1[1] * b[5] + u1g;
            u1g = A1[2] * b[6] + u1g;
            float h12 = A1[4] * b[8];
            h12 = A1[5] * b[9]  + h12;
            h12 = A1[6] * b[10] + h12;

            v2f e12, e1g;
            e12.x = __builtin_amdgcn_exp2f(t12.x);
            e12.y = __builtin_amdgcn_exp2f(t12.y);
            e1g.x = __builtin_amdgcn_exp2f(t1g.x);
            e1g.y = __builtin_amdgcn_exp2f(t1g.y);
            const float f12 = __builtin_amdgcn_exp2f(u12);
            const float f1g = __builtin_amdgcn_exp2f(u1g);

            s2v = e12 * g12 + s2v;
            s4v = e1g * g12 + s4v;
            s2s = f12 * h12 + s2s;
            s4s = f1g * h12 + s4s;
        }

        float r2 = s2v.x + s2v.y + s2s;
        float r4 = s4v.x + s4v.y + s4s;
#pragma unroll
        for (int off = 32; off > 0; off >>= 1) {
            r2 += __shfl_down(r2, off);
            r4 += __shfl_down(r4, off);
        }
        const int wave = t >> 6, lane = t & 63;
        if (lane == 0) { red[wave][0] = r2; red[wave][1] = r4; }
        __syncthreads();
        if (t == 0) {
            pF[0 * NBF + blk] = red[0][0] + red[1][0];
            pF[1 * NBF + blk] = red[0][1] + red[1][1];
        }
    }
}

__global__ __launch_bounds__(256) void finalize_kernel(
    const float* __restrict__ pT, const float* __restrict__ pF,
    float* __restrict__ out)
{
    __shared__ double red[4][5];
    double l0 = 0, l1 = 0, l2 = 0, l3 = 0, l4 = 0;
    for (int b = threadIdx.x; b < NBT; b += 256) {
        l0 += pT[0 * NBT + b];
        l1 += pT[1 * NBT + b];
        l3 += pT[2 * NBT + b];
    }
    for (int b = threadIdx.x; b < NBF; b += 256) {
        l2 += pF[0 * NBF + b];
        l4 += pF[1 * NBF + b];
    }
#pragma unroll
    for (int off = 32; off > 0; off >>= 1) {
        l0 += __shfl_down(l0, off);
        l1 += __shfl_down(l1, off);
        l2 += __shfl_down(l2, off);
        l3 += __shfl_down(l3, off);
        l4 += __shfl_down(l4, off);
    }
    const int wave = threadIdx.x >> 6, lane = threadIdx.x & 63;
    if (lane == 0) {
        red[wave][0] = l0; red[wave][1] = l1; red[wave][2] = l2;
        red[wave][3] = l3; red[wave][4] = l4;
    }
    __syncthreads();
    if (threadIdx.x == 0) {
        const double a0 = red[0][0] + red[1][0] + red[2][0] + red[3][0];
        const double a1 = red[0][1] + red[1][1] + red[2][1] + red[3][1];
        const double a2 = red[0][2] + red[1][2] + red[2][2] + red[3][2];
        const double a3 = red[0][3] + red[1][3] + red[2][3] + red[3][3];
        const double a4 = red[0][4] + red[1][4] + red[2][4] + red[3][4];
        const double num = a0 + a1 - 2.0 * a2;
        const double den = a0 + a3 - 2.0 * a4;
        out[0] = (float)(num / den);
    }
}

extern "C" void kernel_launch(void* const* d_in, const int* in_sizes, int n_in,
                              void* d_out, int out_size, void* d_ws, size_t ws_size,
                              hipStream_t stream)
{
    const float* depth1 = (const float*)d_in[0];
    const float* depth2 = (const float*)d_in[1];
    const float* pose   = (const float*)d_in[2];
    const float* img1   = (const float*)d_in[3];
    const float* img2   = (const float*)d_in[4];
    const float* poseg  = (const float*)d_in[5];

    float* QT  = (float*)d_ws;                       // 6912*20 f = 553 KB
    float* QFn = QT  + (size_t)NPTS * ROWT;          // 6912* 8 f = 221 KB
    float* QFm = QFn + (size_t)NPTS * ROWFN;         // 6912*12 f = 332 KB
    float* pT  = QFm + (size_t)NPTS * ROWFM;         // 3*1512 f
    float* pF  = pT  + 3 * NBT;                      // 2*1944 f

    precompute_kernel<<<NPTS / 256, 256, 0, stream>>>(depth1, depth2, pose,
                                                      img1, img2, poseg,
                                                      QT, QFn, QFm);
    pair_kernel<<<NBLK, BLOCK, 0, stream>>>(QT, QFn, QFm, pT, pF);
    finalize_kernel<<<1, 256, 0, stream>>>(pT, pF, (float*)d_out);
}